// Round 18
// baseline (1061.436 us; speedup 1.0000x reference)
//
#include <hip/hip_runtime.h>
#include <math.h>

#define EMB 300
#define KP 320
#define FEAT 256
#define NLAYER 5
#define NGRAPH 2048
#define BNEPS 1e-5f
#define SCAN_B 256
#define NPART 64
#define CH 40     // 16B chunks per row (k_mm staging)
#define CHW 20    // 32B chunks per row (aggV)

typedef __attribute__((ext_vector_type(8))) short short8;
typedef __attribute__((ext_vector_type(8))) unsigned short ushort8;
typedef __attribute__((ext_vector_type(4))) float f32x4;

#define GLOAD_LDS16(src, dst) __builtin_amdgcn_global_load_lds( \
    (const __attribute__((address_space(1))) unsigned int*)(const void*)(src), \
    (__attribute__((address_space(3))) unsigned int*)(void*)(dst), 16, 0, 0)

static __device__ __forceinline__ unsigned short f2bf(float f) {
    unsigned int u = __float_as_uint(f);
    unsigned int r = (u + 0x7FFFu + ((u >> 16) & 1u)) >> 16;   // RNE
    return (unsigned short)r;
}
static __device__ __forceinline__ float bf2f(unsigned short h) {
    return __uint_as_float(((unsigned int)h) << 16);
}

// ---------------- W prep: transpose to [col][k] bf16, zero pads ----------------
__global__ void k_prepW(const float* __restrict__ convw, const float* __restrict__ featw,
                        unsigned short* __restrict__ whi) {
    int idx = blockIdx.x * 256 + threadIdx.x;
    if (idx >= 1856 * KP) return;
    int row = idx / KP;
    int k = idx - row * KP;
    float w = 0.f;
    if (row < 1600) {
        int l = row / KP;
        int c = row - l * KP;
        if (c < EMB && k < EMB) w = convw[(size_t)l * EMB * EMB + (size_t)k * EMB + c];
    } else {
        int c = row - 1600;
        if (k < EMB) w = featw[(size_t)k * FEAT + c];
    }
    whi[idx] = f2bf(w);
}

// ---------------- edge-attr histogram per dst node: hist[v][0..5]=bond, [6..8]=dir ----
__global__ void k_hist(const int* __restrict__ ei, const int* __restrict__ ea,
                       int* __restrict__ hist, int E) {
    int e = blockIdx.x * 256 + threadIdx.x;
    if (e >= E) return;
    int d = ei[E + e];
    atomicAdd(&hist[(size_t)d * 12 + ea[2 * e]], 1);
    atomicAdd(&hist[(size_t)d * 12 + 6 + ea[2 * e + 1]], 1);
}

// ---------------- expand histogram -> per-node edge-scalar sums (all layers) + deg ----
// s_l(v) = sum_k hist1[v][k]*eemb1[l][k] + sum_k hist2[v][k]*eemb2[l][k] + selfloop_l
// deg[v] = in-degree = sum_k hist1[v][k] (each edge contributes one bond-type count).
__global__ void k_sexp(const int* __restrict__ hist, const float* __restrict__ eemb1,
                       const float* __restrict__ eemb2, float* __restrict__ s,
                       int* __restrict__ deg, int N) {
    int v = blockIdx.x * 256 + threadIdx.x;
    if (v >= N) return;
    int h[12];
#pragma unroll
    for (int k = 0; k < 12; ++k) h[k] = hist[(size_t)v * 12 + k];
    deg[v] = h[0] + h[1] + h[2] + h[3] + h[4] + h[5];
#pragma unroll
    for (int l = 0; l < NLAYER; ++l) {
        float acc = eemb1[l * 6 + 4] + eemb2[l * 3 + 0];   // self loop: type 4, dir 0
#pragma unroll
        for (int k = 0; k < 6; ++k) acc += (float)h[k] * eemb1[l * 6 + k];
#pragma unroll
        for (int k = 0; k < 3; ++k) acc += (float)h[6 + k] * eemb2[l * 3 + k];
        s[(size_t)l * N + v] = acc;
    }
}

// ---------------- CSR build ----------------
__global__ void k_scanA(const int* __restrict__ deg, int* __restrict__ bsum, int N) {
    __shared__ int sm[SCAN_B];
    int i = blockIdx.x * SCAN_B + threadIdx.x;
    sm[threadIdx.x] = (i < N) ? deg[i] : 0;
    __syncthreads();
    for (int off = SCAN_B / 2; off > 0; off >>= 1) {
        if (threadIdx.x < off) sm[threadIdx.x] += sm[threadIdx.x + off];
        __syncthreads();
    }
    if (threadIdx.x == 0) bsum[blockIdx.x] = sm[0];
}

__global__ void k_scanB(int* __restrict__ bsum, int nb, int* __restrict__ rowptr, int N) {
    if (threadIdx.x == 0 && blockIdx.x == 0) {
        int acc = 0;
        for (int i = 0; i < nb; ++i) { int v = bsum[i]; bsum[i] = acc; acc += v; }
        rowptr[N] = acc;
    }
}

__global__ void k_scanC(const int* __restrict__ deg, const int* __restrict__ bsum,
                        int* __restrict__ rowptr, int N) {
    __shared__ int sm[SCAN_B];
    int i = blockIdx.x * SCAN_B + threadIdx.x;
    int v = (i < N) ? deg[i] : 0;
    sm[threadIdx.x] = v;
    __syncthreads();
    for (int off = 1; off < SCAN_B; off <<= 1) {
        int add = (threadIdx.x >= off) ? sm[threadIdx.x - off] : 0;
        __syncthreads();
        sm[threadIdx.x] += add;
        __syncthreads();
    }
    if (i < N) rowptr[i] = bsum[blockIdx.x] + sm[threadIdx.x] - v;
}

__global__ void k_scatter(const int* __restrict__ ei, const int* __restrict__ rowptr,
                          int* __restrict__ cursor, int* __restrict__ esrc, int E) {
    int e = blockIdx.x * blockDim.x + threadIdx.x;
    if (e >= E) return;
    int d = ei[E + e], srcv = ei[e];
    int p = atomicAdd(&cursor[d], 1);
    esrc[rowptr[d] + p] = srcv;
}

// ---------------- h0 = emb1[x0] + emb2[x1], bf16, KP-padded (pads zero) ----------------
__global__ void k_h0(const int* __restrict__ x, const float* __restrict__ emb1,
                     const float* __restrict__ emb2, unsigned short* __restrict__ h0, int N) {
    int idx = blockIdx.x * 256 + threadIdx.x;
    if (idx >= N * 160) return;
    int v = idx / 160, fp = idx - v * 160;
    unsigned int out = 0;
    if (fp < 150) {
        int f = fp * 2;
        size_t b1 = (size_t)x[2 * v] * EMB + f;
        size_t b2 = (size_t)x[2 * v + 1] * EMB + f;
        float a = emb1[b1] + emb2[b2];
        float b = emb1[b1 + 1] + emb2[b2 + 1];
        out = (unsigned int)f2bf(a) | ((unsigned int)f2bf(b) << 16);
    }
    *(unsigned int*)(h0 + (size_t)v * KP + fp * 2) = out;
}

// ---------------- vectorized gather-aggregation, 32B chunks ----------------
// A[v] = t(Prev[v]) + sum_u t(Prev[u]); t = relu(BN(.)) when BN, identity otherwise.
template <bool BN>
__global__ __launch_bounds__(256) void k_aggV(
    const unsigned short* __restrict__ Prev, const int* __restrict__ rowptr,
    const int* __restrict__ esrc,
    const float* __restrict__ scale, const float* __restrict__ shift,
    unsigned short* __restrict__ A, int N) {
    int idx = blockIdx.x * 256 + threadIdx.x;
    if (idx >= N * CHW) return;
    int row = idx / CHW, c = idx - row * CHW;
    int f0 = c * 16;

    f32x4 sc[4], sh[4];
    if constexpr (BN) {
#pragma unroll
        for (int g = 0; g < 4; ++g) {
            sc[g] = *(const f32x4*)(scale + f0 + g * 4);
            sh[g] = *(const f32x4*)(shift + f0 + g * 4);
        }
    }
    int rs = rowptr[row], re = rowptr[row + 1];

    float f[16];
    {
        const unsigned short* pr = Prev + (size_t)row * KP + f0;
        ushort8 u0 = *(const ushort8*)pr;
        ushort8 u1 = *(const ushort8*)(pr + 8);
#pragma unroll
        for (int e = 0; e < 8; ++e) {
            if constexpr (BN) {
                f[e]     = fmaxf(fmaf(bf2f(u0[e]), sc[e >> 2][e & 3], sh[e >> 2][e & 3]), 0.f);
                f[e + 8] = fmaxf(fmaf(bf2f(u1[e]), sc[2 + (e >> 2)][e & 3], sh[2 + (e >> 2)][e & 3]), 0.f);
            } else {
                f[e] = bf2f(u0[e]);
                f[e + 8] = bf2f(u1[e]);
            }
        }
    }
    int ii = rs;
    int un = (ii < re) ? esrc[ii] : 0;
    while (ii < re) {
        int ucur = un;
        ++ii;
        if (ii < re) un = esrc[ii];          // prefetch next index
        const unsigned short* pu = Prev + (size_t)ucur * KP + f0;
        ushort8 uu0 = *(const ushort8*)pu;        // two independent 16B loads
        ushort8 uu1 = *(const ushort8*)(pu + 8);
#pragma unroll
        for (int e = 0; e < 8; ++e) {
            if constexpr (BN) {
                f[e]     += fmaxf(fmaf(bf2f(uu0[e]), sc[e >> 2][e & 3], sh[e >> 2][e & 3]), 0.f);
                f[e + 8] += fmaxf(fmaf(bf2f(uu1[e]), sc[2 + (e >> 2)][e & 3], sh[2 + (e >> 2)][e & 3]), 0.f);
            } else {
                f[e] += bf2f(uu0[e]);
                f[e + 8] += bf2f(uu1[e]);
            }
        }
    }
    short8 v0, v1;
#pragma unroll
    for (int e = 0; e < 8; ++e) {
        v0[e] = (short)f2bf(f[e]);
        v1[e] = (short)f2bf(f[e + 8]);
    }
    unsigned short* dst = A + (size_t)row * KP + f0;
    *(short8*)dst = v0;
    *(short8*)(dst + 8) = v1;
}

// ---------------- MFMA GEMM (R10/R13 proven shape) + fused last-block BN reduce --------
// 256 thr = 4 waves; BMT=128 rows; full K=320 in LDS (80KB, XOR-swizzled 16B chunks).
// Conv (!BN): DMA staging via global_load_lds(16B), source chunk pre-swizzled c^(r&7),
//   LDS linear (Abf tail rows zeroed once in kernel_launch). acc[8][5]. After the
//   partial-stat atomics + writeback, the LAST block (donecnt) reduces the 64 partials
//   into scale/shift for the next layer (replaces the separate k_bnred dispatch).
// Feat (BN): reg staging with BN+relu transform. acc[8][4].
// Epilogue routes through LDS so global stores are contiguous full rows (short8).
template <int COLF, int BMT, bool BN>
__global__ __launch_bounds__(256, 2) void k_mm(
    const unsigned short* __restrict__ Prev,
    const float* __restrict__ scale, const float* __restrict__ shift,
    const unsigned short* __restrict__ Whi,
    const float* __restrict__ bias, const float* __restrict__ svec,
    unsigned short* __restrict__ OutB,
    float* __restrict__ partsum, float* __restrict__ partsq,
    const float* __restrict__ gamma, const float* __restrict__ beta,
    float* __restrict__ scaleOut, float* __restrict__ shiftOut,
    int* __restrict__ donecnt, int nblk, int N) {
    __shared__ unsigned short As[BMT * KP];
    constexpr int WSTR = (COLF == 5) ? KP : FEAT;
    constexpr int RF = BMT / 16;
    constexpr int NCHUNK = BMT * CH;
    int tid = threadIdx.x;
    int row0 = blockIdx.x * BMT;
    int wave = tid >> 6, lane = tid & 63;

    // ---- stage ----
    if constexpr (!BN) {
        // DMA: wave-uniform LDS base + lane*16; source chunk pre-swizzled.
#pragma unroll
        for (int it = 0; it < NCHUNK / 256; ++it) {
            int base = it * 256 + wave * 64;           // chunk index of lane 0
            int idx = base + lane;
            int r = idx / CH, c = idx - r * CH;
            const unsigned short* src =
                Prev + (size_t)(row0 + r) * KP + (size_t)(c ^ (r & 7)) * 8;
            GLOAD_LDS16(src, &As[(size_t)base * 8]);
        }
    } else {
        for (int idx = tid; idx < NCHUNK; idx += 256) {
            int r = idx / CH, c = idx - r * CH;
            int row = row0 + r;
            short8 v = (short8){0, 0, 0, 0, 0, 0, 0, 0};
            if (row < N) {
                ushort8 u = *(const ushort8*)(Prev + (size_t)row * KP + c * 8);
                f32x4 s0 = *(const f32x4*)(scale + c * 8);
                f32x4 s1 = *(const f32x4*)(scale + c * 8 + 4);
                f32x4 t0 = *(const f32x4*)(shift + c * 8);
                f32x4 t1 = *(const f32x4*)(shift + c * 8 + 4);
#pragma unroll
                for (int e = 0; e < 4; ++e) {
                    v[e]     = (short)f2bf(fmaxf(fmaf(bf2f(u[e]), s0[e], t0[e]), 0.f));
                    v[e + 4] = (short)f2bf(fmaxf(fmaf(bf2f(u[e + 4]), s1[e], t1[e]), 0.f));
                }
            }
            *(short8*)&As[(size_t)(r * CH + (c ^ (r & 7))) * 8] = v;
        }
    }
    __syncthreads();

    int q = lane >> 4, m = lane & 15;
    int wbase = wave * (COLF * 16);

    f32x4 acc[RF][COLF];
#pragma unroll
    for (int rf = 0; rf < RF; ++rf)
#pragma unroll
        for (int cf = 0; cf < COLF; ++cf)
            acc[rf][cf] = (f32x4){0.f, 0.f, 0.f, 0.f};

    size_t woff[COLF];
#pragma unroll
    for (int cf = 0; cf < COLF; ++cf)
        woff[cf] = (size_t)(wbase + cf * 16 + m) * KP;

#pragma unroll 2
    for (int ks = 0; ks < 10; ++ks) {
        short8 a[RF];
#pragma unroll
        for (int rf = 0; rf < RF; ++rf) {
            int r = rf * 16 + m;
            int ch = ks * 4 + q;
            a[rf] = *(const short8*)&As[(size_t)(r * CH + (ch ^ (r & 7))) * 8];
        }
        int kb = ks * 32 + q * 8;
#pragma unroll
        for (int cf = 0; cf < COLF; ++cf) {
            short8 bh = *(const short8*)(Whi + woff[cf] + kb);
#pragma unroll
            for (int rf = 0; rf < RF; ++rf) {
                acc[rf][cf] = __builtin_amdgcn_mfma_f32_16x16x32_bf16(a[rf], bh, acc[rf][cf], 0, 0, 0);
            }
        }
    }

    __syncthreads();   // done reading As; reuse it as the write-back tile

    // ---- epilogue: D lane map col=lane&15, row=(lane>>4)*4+reg ----
    if constexpr (COLF == 5) {
        float sv[RF][4];
#pragma unroll
        for (int rf = 0; rf < RF; ++rf)
#pragma unroll
            for (int i = 0; i < 4; ++i) {
                int row = row0 + rf * 16 + q * 4 + i;
                sv[rf][i] = (row < N) ? svec[row] : 0.f;
            }
        int part = blockIdx.x & (NPART - 1);
#pragma unroll
        for (int cf = 0; cf < COLF; ++cf) {
            int col = wbase + cf * 16 + m;
            bool cok = col < EMB;
            float bia = cok ? bias[col] : 0.f;
            float lsum = 0.f, lsq = 0.f;
#pragma unroll
            for (int rf = 0; rf < RF; ++rf)
#pragma unroll
                for (int i = 0; i < 4; ++i) {
                    int r = rf * 16 + q * 4 + i;
                    int row = row0 + r;
                    float val = 0.f;
                    if (cok && row < N) {
                        val = acc[rf][cf][i] + bia + sv[rf][i];
                        lsum += val; lsq += val * val;
                    }
                    As[(size_t)r * WSTR + col] = f2bf(val);
                }
            lsum += __shfl_xor(lsum, 16); lsum += __shfl_xor(lsum, 32);
            lsq  += __shfl_xor(lsq, 16);  lsq  += __shfl_xor(lsq, 32);
            if (q == 0 && cok) {
                atomicAdd(&partsum[(size_t)part * KP + col], lsum);
                atomicAdd(&partsq[(size_t)part * KP + col], lsq);
            }
        }
    } else {
#pragma unroll
        for (int cf = 0; cf < COLF; ++cf) {
            int col = wbase + cf * 16 + m;
            float bia = bias[col];
#pragma unroll
            for (int rf = 0; rf < RF; ++rf)
#pragma unroll
                for (int i = 0; i < 4; ++i) {
                    int r = rf * 16 + q * 4 + i;
                    As[(size_t)r * WSTR + col] = f2bf(acc[rf][cf][i] + bia);
                }
        }
    }
    __syncthreads();

    // ---- contiguous write-back: BMT*WSTR bf16, full 16B chunks ----
    unsigned short* dst = OutB + (size_t)row0 * WSTR;
    for (int idx = tid; idx < BMT * WSTR / 8; idx += 256) {
        *(short8*)(dst + (size_t)idx * 8) = *(const short8*)&As[(size_t)idx * 8];
    }

    // ---- fused BN reduce: last block to finish computes scale/shift ----
    if constexpr (COLF == 5) {
        __shared__ int lastFlag;
        __syncthreads();                       // drains the partial-stat atomics too
        if (tid == 0) {
            __threadfence();                   // release: partials visible device-wide
            int old = atomicAdd(donecnt, 1);
            lastFlag = (old == nblk - 1) ? 1 : 0;
        }
        __syncthreads();
        if (lastFlag) {
            __threadfence();                   // acquire side
            float invN = 1.0f / (float)N;
            for (int j = tid; j < KP; j += 256) {
                if (j < EMB) {
                    float s = 0.f, sq = 0.f;
                    for (int pp = 0; pp < NPART; ++pp) {
                        s  += partsum[(size_t)pp * KP + j];
                        sq += partsq[(size_t)pp * KP + j];
                    }
                    float mean = s * invN;
                    float var = sq * invN - mean * mean;
                    float scv = gamma[j] * rsqrtf(var + BNEPS);
                    scaleOut[j] = scv;
                    shiftOut[j] = beta[j] - mean * scv;
                } else {
                    scaleOut[j] = 0.f;
                    shiftOut[j] = 0.f;
                }
            }
        }
    }
}

// ---------------- pooling over sorted batch (run-length compressed atomics) -------------
// counts fused in: lane 0 of each run adds the run length (1 atomic per run per block).
#define PROWS 128
__global__ __launch_bounds__(256) void k_pool(const unsigned short* __restrict__ H,
                                              const int* __restrict__ batch,
                                              float* __restrict__ gsums,
                                              float* __restrict__ counts, int N) {
    int j = threadIdx.x;
    int r0 = blockIdx.x * PROWS;
    int rend = min(r0 + PROWS, N);
    float run = 0.f;
    int runlen = 0;
    int curg = -1;
    for (int r = r0; r < rend; ++r) {
        int g = batch[r];
        if (g != curg) {
            if (curg >= 0) {
                atomicAdd(&gsums[(size_t)curg * FEAT + j], run);
                if (j == 0) atomicAdd(&counts[curg], (float)runlen);
            }
            curg = g; run = 0.f; runlen = 0;
        }
        run += bf2f(H[(size_t)r * FEAT + j]);
        ++runlen;
    }
    if (curg >= 0) {
        atomicAdd(&gsums[(size_t)curg * FEAT + j], run);
        if (j == 0) atomicAdd(&counts[curg], (float)runlen);
    }
}

// ---------------- pool-finalize + 2-layer MLP head, one block per graph ----------------
__global__ __launch_bounds__(128) void k_pred(
    const float* __restrict__ gsums, const float* __restrict__ counts,
    const float* __restrict__ w1, const float* __restrict__ b1,
    const float* __restrict__ w2, const float* __restrict__ b2,
    float* __restrict__ gout, float* __restrict__ pout) {
    __shared__ float gs[FEAT];
    __shared__ float h1[128];
    int g = blockIdx.x;
    float invc = 1.0f / fmaxf(counts[g], 1.0f);
    for (int k = threadIdx.x; k < FEAT; k += 128) {
        float val = gsums[(size_t)g * FEAT + k] * invc;
        gs[k] = val;
        gout[(size_t)g * FEAT + k] = val;
    }
    __syncthreads();
    int j = threadIdx.x;
    float acc = b1[j];
    for (int k = 0; k < FEAT; ++k) acc = fmaf(gs[k], w1[(size_t)k * 128 + j], acc);
    h1[j] = fmaxf(acc, 0.f);
    __syncthreads();
    if (j < 2) {
        float acc2 = b2[j];
        for (int k = 0; k < 128; ++k) acc2 = fmaf(h1[k], w2[k * 2 + j], acc2);
        pout[(size_t)g * 2 + j] = acc2;
    }
}

extern "C" void kernel_launch(void* const* d_in, const int* in_sizes, int n_in,
                              void* d_out, int out_size, void* d_ws, size_t ws_size,
                              hipStream_t stream) {
    const int* x      = (const int*)d_in[0];
    const int* ei     = (const int*)d_in[1];
    const int* ea     = (const int*)d_in[2];
    const int* batch  = (const int*)d_in[3];
    const float* xemb1 = (const float*)d_in[4];
    const float* xemb2 = (const float*)d_in[5];
    const float* convw = (const float*)d_in[6];
    const float* convb = (const float*)d_in[7];
    const float* eemb1 = (const float*)d_in[8];
    const float* eemb2 = (const float*)d_in[9];
    const float* gamma = (const float*)d_in[10];
    const float* beta  = (const float*)d_in[11];
    const float* featw = (const float*)d_in[12];
    const float* featb = (const float*)d_in[13];
    const float* pw1   = (const float*)d_in[14];
    const float* pb1   = (const float*)d_in[15];
    const float* pw2   = (const float*)d_in[16];
    const float* pb2   = (const float*)d_in[17];

    int N = in_sizes[0] / 2;
    int E = in_sizes[1] / 2;
    int nrb = (N + 127) / 128;            // both GEMMs use BMT=128
    size_t Npad = (size_t)nrb * 128;

    char* p = (char*)d_ws;
    auto alloc = [&](size_t bytes) { char* r = p; p += (bytes + 255) & ~255ull; return r; };
    // H0 (layer-0 input) and Hf (feature output) have disjoint live ranges -> share 64MB.
    unsigned short* H0Hf = (unsigned short*)alloc(Npad * KP * 2);    // 64 MB shared
    unsigned short* Abf  = (unsigned short*)alloc(Npad * KP * 2);    // 64 MB
    unsigned short* OutB = (unsigned short*)alloc(Npad * KP * 2);    // 64 MB
    float* partsum = (float*)alloc((size_t)NLAYER * NPART * KP * 4);
    float* partsq  = (float*)alloc((size_t)NLAYER * NPART * KP * 4);
    char*  zero1_end = p;                                            // partsum..partsq contiguous
    float* sAll    = (float*)alloc((size_t)NLAYER * N * 4);          // fully overwritten by k_sexp
    float* scaleA  = (float*)alloc((size_t)NLAYER * KP * 4);
    float* shiftA  = (float*)alloc((size_t)NLAYER * KP * 4);
    unsigned short* Whi = (unsigned short*)alloc((size_t)1856 * KP * 2);
    int*   deg    = (int*)alloc((size_t)N * 4);                      // written by k_sexp
    int*   rowptr = (int*)alloc((size_t)(N + 1) * 4);
    int*   cursor = (int*)alloc((size_t)N * 4);
    int*   donecnt = (int*)alloc((size_t)NLAYER * 4);
    int*   hist   = (int*)alloc((size_t)N * 12 * 4);
    char*  zero2_end = p;                                            // cursor..hist contiguous
    int*   esrc   = (int*)alloc((size_t)E * 4);
    float* gsums  = (float*)alloc((size_t)NGRAPH * FEAT * 4);
    float* counts = (float*)alloc(NGRAPH * 4);
    char*  zero3_end = p;                                            // gsums..counts contiguous
    int nb = (N + SCAN_B - 1) / SCAN_B;
    int*   bsum   = (int*)alloc((size_t)nb * 4);

    hipMemsetAsync(partsum, 0, (size_t)(zero1_end - (char*)partsum), stream);
    hipMemsetAsync(cursor, 0, (size_t)(zero2_end - (char*)cursor), stream);  // cursor+donecnt+hist
    hipMemsetAsync(gsums, 0, (size_t)(zero3_end - (char*)gsums), stream);
    // DMA staging reads Abf tail rows unguarded -> keep them zero (aggV only writes rows <N)
    if (Npad > (size_t)N)
        hipMemsetAsync(Abf + (size_t)N * KP, 0, (Npad - (size_t)N) * KP * 2, stream);

    int tpb = 256;
    k_prepW<<<(1856 * KP + 255) / 256, 256, 0, stream>>>(convw, featw, Whi);
    k_hist<<<(E + 255) / 256, 256, 0, stream>>>(ei, ea, hist, E);
    k_sexp<<<(N + 255) / 256, 256, 0, stream>>>(hist, eemb1, eemb2, sAll, deg, N);
    k_scanA<<<nb, SCAN_B, 0, stream>>>(deg, bsum, N);
    k_scanB<<<1, 64, 0, stream>>>(bsum, nb, rowptr, N);
    k_scanC<<<nb, SCAN_B, 0, stream>>>(deg, bsum, rowptr, N);
    k_scatter<<<(E + tpb - 1) / tpb, tpb, 0, stream>>>(ei, rowptr, cursor, esrc, E);
    k_h0<<<(N * 160 + 255) / 256, 256, 0, stream>>>(x, xemb1, xemb2, H0Hf, N);

    int gagg = (N * CHW + 255) / 256;
    k_aggV<false><<<gagg, 256, 0, stream>>>(H0Hf, rowptr, esrc, nullptr, nullptr, Abf, N);

    for (int l = 0; l < NLAYER; ++l) {
        k_mm<5, 128, false><<<nrb, 256, 0, stream>>>(
            Abf, nullptr, nullptr,
            Whi + (size_t)l * KP * KP,
            convb + (size_t)l * EMB, sAll + (size_t)l * N,
            OutB,
            partsum + (size_t)l * NPART * KP, partsq + (size_t)l * NPART * KP,
            gamma + (size_t)l * EMB, beta + (size_t)l * EMB,
            scaleA + (size_t)l * KP, shiftA + (size_t)l * KP,
            donecnt + l, nrb, N);
        if (l < NLAYER - 1)
            k_aggV<true><<<gagg, 256, 0, stream>>>(OutB, rowptr, esrc,
                                                   scaleA + (size_t)l * KP, shiftA + (size_t)l * KP,
                                                   Abf, N);
    }

    k_mm<4, 128, true><<<nrb, 256, 0, stream>>>(
        OutB, scaleA + (size_t)4 * KP, shiftA + (size_t)4 * KP,
        Whi + (size_t)1600 * KP,
        featb, nullptr,
        H0Hf, nullptr, nullptr, nullptr, nullptr, nullptr, nullptr, nullptr, 0, N);

    float* gout = (float*)d_out;
    float* pout = gout + (size_t)NGRAPH * FEAT;
    k_pool<<<(N + PROWS - 1) / PROWS, 256, 0, stream>>>(H0Hf, batch, gsums, counts, N);
    k_pred<<<NGRAPH, 128, 0, stream>>>(gsums, counts, pw1, pb1, pw2, pb2, gout, pout);
}

// Round 19
// 737.108 us; speedup vs baseline: 1.4400x; 1.4400x over previous
//
#include <hip/hip_runtime.h>
#include <math.h>

#define EMB 300
#define KP 320
#define FEAT 256
#define NLAYER 5
#define NGRAPH 2048
#define BNEPS 1e-5f
#define SCAN_B 256
#define NPART 64
#define CH 40     // 16B chunks per row (k_mm staging)
#define CHW 20    // 32B chunks per row (aggV)

typedef __attribute__((ext_vector_type(8))) short short8;
typedef __attribute__((ext_vector_type(8))) unsigned short ushort8;
typedef __attribute__((ext_vector_type(4))) float f32x4;

#define GLOAD_LDS16(src, dst) __builtin_amdgcn_global_load_lds( \
    (const __attribute__((address_space(1))) unsigned int*)(const void*)(src), \
    (__attribute__((address_space(3))) unsigned int*)(void*)(dst), 16, 0, 0)

static __device__ __forceinline__ unsigned short f2bf(float f) {
    unsigned int u = __float_as_uint(f);
    unsigned int r = (u + 0x7FFFu + ((u >> 16) & 1u)) >> 16;   // RNE
    return (unsigned short)r;
}
static __device__ __forceinline__ float bf2f(unsigned short h) {
    return __uint_as_float(((unsigned int)h) << 16);
}

// ---------------- W prep: transpose to [col][k] bf16, zero pads ----------------
__global__ void k_prepW(const float* __restrict__ convw, const float* __restrict__ featw,
                        unsigned short* __restrict__ whi) {
    int idx = blockIdx.x * 256 + threadIdx.x;
    if (idx >= 1856 * KP) return;
    int row = idx / KP;
    int k = idx - row * KP;
    float w = 0.f;
    if (row < 1600) {
        int l = row / KP;
        int c = row - l * KP;
        if (c < EMB && k < EMB) w = convw[(size_t)l * EMB * EMB + (size_t)k * EMB + c];
    } else {
        int c = row - 1600;
        if (k < EMB) w = featw[(size_t)k * FEAT + c];
    }
    whi[idx] = f2bf(w);
}

// ---------------- edge-attr histogram per dst node: hist[v][0..5]=bond, [6..8]=dir ----
__global__ void k_hist(const int* __restrict__ ei, const int* __restrict__ ea,
                       int* __restrict__ hist, int E) {
    int e = blockIdx.x * 256 + threadIdx.x;
    if (e >= E) return;
    int d = ei[E + e];
    atomicAdd(&hist[(size_t)d * 12 + ea[2 * e]], 1);
    atomicAdd(&hist[(size_t)d * 12 + 6 + ea[2 * e + 1]], 1);
}

// ---------------- expand histogram -> per-node edge-scalar sums (all layers) + deg ----
__global__ void k_sexp(const int* __restrict__ hist, const float* __restrict__ eemb1,
                       const float* __restrict__ eemb2, float* __restrict__ s,
                       int* __restrict__ deg, int N) {
    int v = blockIdx.x * 256 + threadIdx.x;
    if (v >= N) return;
    int h[12];
#pragma unroll
    for (int k = 0; k < 12; ++k) h[k] = hist[(size_t)v * 12 + k];
    deg[v] = h[0] + h[1] + h[2] + h[3] + h[4] + h[5];
#pragma unroll
    for (int l = 0; l < NLAYER; ++l) {
        float acc = eemb1[l * 6 + 4] + eemb2[l * 3 + 0];   // self loop: type 4, dir 0
#pragma unroll
        for (int k = 0; k < 6; ++k) acc += (float)h[k] * eemb1[l * 6 + k];
#pragma unroll
        for (int k = 0; k < 3; ++k) acc += (float)h[6 + k] * eemb2[l * 3 + k];
        s[(size_t)l * N + v] = acc;
    }
}

// ---------------- CSR build ----------------
__global__ void k_scanA(const int* __restrict__ deg, int* __restrict__ bsum, int N) {
    __shared__ int sm[SCAN_B];
    int i = blockIdx.x * SCAN_B + threadIdx.x;
    sm[threadIdx.x] = (i < N) ? deg[i] : 0;
    __syncthreads();
    for (int off = SCAN_B / 2; off > 0; off >>= 1) {
        if (threadIdx.x < off) sm[threadIdx.x] += sm[threadIdx.x + off];
        __syncthreads();
    }
    if (threadIdx.x == 0) bsum[blockIdx.x] = sm[0];
}

__global__ void k_scanB(int* __restrict__ bsum, int nb, int* __restrict__ rowptr, int N) {
    if (threadIdx.x == 0 && blockIdx.x == 0) {
        int acc = 0;
        for (int i = 0; i < nb; ++i) { int v = bsum[i]; bsum[i] = acc; acc += v; }
        rowptr[N] = acc;
    }
}

__global__ void k_scanC(const int* __restrict__ deg, const int* __restrict__ bsum,
                        int* __restrict__ rowptr, int N) {
    __shared__ int sm[SCAN_B];
    int i = blockIdx.x * SCAN_B + threadIdx.x;
    int v = (i < N) ? deg[i] : 0;
    sm[threadIdx.x] = v;
    __syncthreads();
    for (int off = 1; off < SCAN_B; off <<= 1) {
        int add = (threadIdx.x >= off) ? sm[threadIdx.x - off] : 0;
        __syncthreads();
        sm[threadIdx.x] += add;
        __syncthreads();
    }
    if (i < N) rowptr[i] = bsum[blockIdx.x] + sm[threadIdx.x] - v;
}

__global__ void k_scatter(const int* __restrict__ ei, const int* __restrict__ rowptr,
                          int* __restrict__ cursor, int* __restrict__ esrc, int E) {
    int e = blockIdx.x * blockDim.x + threadIdx.x;
    if (e >= E) return;
    int d = ei[E + e], srcv = ei[e];
    int p = atomicAdd(&cursor[d], 1);
    esrc[rowptr[d] + p] = srcv;
}

// ---------------- h0 = emb1[x0] + emb2[x1], bf16, KP-padded (pads zero) ----------------
__global__ void k_h0(const int* __restrict__ x, const float* __restrict__ emb1,
                     const float* __restrict__ emb2, unsigned short* __restrict__ h0, int N) {
    int idx = blockIdx.x * 256 + threadIdx.x;
    if (idx >= N * 160) return;
    int v = idx / 160, fp = idx - v * 160;
    unsigned int out = 0;
    if (fp < 150) {
        int f = fp * 2;
        size_t b1 = (size_t)x[2 * v] * EMB + f;
        size_t b2 = (size_t)x[2 * v + 1] * EMB + f;
        float a = emb1[b1] + emb2[b2];
        float b = emb1[b1 + 1] + emb2[b2 + 1];
        out = (unsigned int)f2bf(a) | ((unsigned int)f2bf(b) << 16);
    }
    *(unsigned int*)(h0 + (size_t)v * KP + fp * 2) = out;
}

// ---------------- vectorized gather-aggregation, 32B chunks ----------------
template <bool BN>
__global__ __launch_bounds__(256) void k_aggV(
    const unsigned short* __restrict__ Prev, const int* __restrict__ rowptr,
    const int* __restrict__ esrc,
    const float* __restrict__ scale, const float* __restrict__ shift,
    unsigned short* __restrict__ A, int N) {
    int idx = blockIdx.x * 256 + threadIdx.x;
    if (idx >= N * CHW) return;
    int row = idx / CHW, c = idx - row * CHW;
    int f0 = c * 16;

    f32x4 sc[4], sh[4];
    if constexpr (BN) {
#pragma unroll
        for (int g = 0; g < 4; ++g) {
            sc[g] = *(const f32x4*)(scale + f0 + g * 4);
            sh[g] = *(const f32x4*)(shift + f0 + g * 4);
        }
    }
    int rs = rowptr[row], re = rowptr[row + 1];

    float f[16];
    {
        const unsigned short* pr = Prev + (size_t)row * KP + f0;
        ushort8 u0 = *(const ushort8*)pr;
        ushort8 u1 = *(const ushort8*)(pr + 8);
#pragma unroll
        for (int e = 0; e < 8; ++e) {
            if constexpr (BN) {
                f[e]     = fmaxf(fmaf(bf2f(u0[e]), sc[e >> 2][e & 3], sh[e >> 2][e & 3]), 0.f);
                f[e + 8] = fmaxf(fmaf(bf2f(u1[e]), sc[2 + (e >> 2)][e & 3], sh[2 + (e >> 2)][e & 3]), 0.f);
            } else {
                f[e] = bf2f(u0[e]);
                f[e + 8] = bf2f(u1[e]);
            }
        }
    }
    int ii = rs;
    int un = (ii < re) ? esrc[ii] : 0;
    while (ii < re) {
        int ucur = un;
        ++ii;
        if (ii < re) un = esrc[ii];          // prefetch next index
        const unsigned short* pu = Prev + (size_t)ucur * KP + f0;
        ushort8 uu0 = *(const ushort8*)pu;        // two independent 16B loads
        ushort8 uu1 = *(const ushort8*)(pu + 8);
#pragma unroll
        for (int e = 0; e < 8; ++e) {
            if constexpr (BN) {
                f[e]     += fmaxf(fmaf(bf2f(uu0[e]), sc[e >> 2][e & 3], sh[e >> 2][e & 3]), 0.f);
                f[e + 8] += fmaxf(fmaf(bf2f(uu1[e]), sc[2 + (e >> 2)][e & 3], sh[2 + (e >> 2)][e & 3]), 0.f);
            } else {
                f[e] += bf2f(uu0[e]);
                f[e + 8] += bf2f(uu1[e]);
            }
        }
    }
    short8 v0, v1;
#pragma unroll
    for (int e = 0; e < 8; ++e) {
        v0[e] = (short)f2bf(f[e]);
        v1[e] = (short)f2bf(f[e + 8]);
    }
    unsigned short* dst = A + (size_t)row * KP + f0;
    *(short8*)dst = v0;
    *(short8*)(dst + 8) = v1;
}

// ---------------- MFMA GEMM (R10/R13/R17 proven shape) ----------------
// 256 thr = 4 waves; BMT=128 rows; full K=320 in LDS (80KB, XOR-swizzled 16B chunks).
// Conv (!BN): DMA staging via global_load_lds(16B), source chunk pre-swizzled c^(r&7),
//   LDS linear (Abf tail rows zeroed once in kernel_launch). acc[8][5].
// Feat (BN): reg staging with BN+relu transform. acc[8][4].
// Epilogue routes through LDS so global stores are contiguous full rows (short8).
// NOTE: BN-stat reduce stays a SEPARATE k_bnred dispatch — R18's fused last-block
// reduce inflated VGPR 120->208 and halved occupancy (63->132us). Guideline 6.
template <int COLF, int BMT, bool BN>
__global__ __launch_bounds__(256, 2) void k_mm(
    const unsigned short* __restrict__ Prev,
    const float* __restrict__ scale, const float* __restrict__ shift,
    const unsigned short* __restrict__ Whi,
    const float* __restrict__ bias, const float* __restrict__ svec,
    unsigned short* __restrict__ OutB,
    float* __restrict__ partsum, float* __restrict__ partsq, int N) {
    __shared__ unsigned short As[BMT * KP];
    constexpr int WSTR = (COLF == 5) ? KP : FEAT;
    constexpr int RF = BMT / 16;
    constexpr int NCHUNK = BMT * CH;
    int tid = threadIdx.x;
    int row0 = blockIdx.x * BMT;
    int wave = tid >> 6, lane = tid & 63;

    // ---- stage ----
    if constexpr (!BN) {
        // DMA: wave-uniform LDS base + lane*16; source chunk pre-swizzled.
#pragma unroll
        for (int it = 0; it < NCHUNK / 256; ++it) {
            int base = it * 256 + wave * 64;           // chunk index of lane 0
            int idx = base + lane;
            int r = idx / CH, c = idx - r * CH;
            const unsigned short* src =
                Prev + (size_t)(row0 + r) * KP + (size_t)(c ^ (r & 7)) * 8;
            GLOAD_LDS16(src, &As[(size_t)base * 8]);
        }
    } else {
        for (int idx = tid; idx < NCHUNK; idx += 256) {
            int r = idx / CH, c = idx - r * CH;
            int row = row0 + r;
            short8 v = (short8){0, 0, 0, 0, 0, 0, 0, 0};
            if (row < N) {
                ushort8 u = *(const ushort8*)(Prev + (size_t)row * KP + c * 8);
                f32x4 s0 = *(const f32x4*)(scale + c * 8);
                f32x4 s1 = *(const f32x4*)(scale + c * 8 + 4);
                f32x4 t0 = *(const f32x4*)(shift + c * 8);
                f32x4 t1 = *(const f32x4*)(shift + c * 8 + 4);
#pragma unroll
                for (int e = 0; e < 4; ++e) {
                    v[e]     = (short)f2bf(fmaxf(fmaf(bf2f(u[e]), s0[e], t0[e]), 0.f));
                    v[e + 4] = (short)f2bf(fmaxf(fmaf(bf2f(u[e + 4]), s1[e], t1[e]), 0.f));
                }
            }
            *(short8*)&As[(size_t)(r * CH + (c ^ (r & 7))) * 8] = v;
        }
    }
    __syncthreads();

    int q = lane >> 4, m = lane & 15;
    int wbase = wave * (COLF * 16);

    f32x4 acc[RF][COLF];
#pragma unroll
    for (int rf = 0; rf < RF; ++rf)
#pragma unroll
        for (int cf = 0; cf < COLF; ++cf)
            acc[rf][cf] = (f32x4){0.f, 0.f, 0.f, 0.f};

    size_t woff[COLF];
#pragma unroll
    for (int cf = 0; cf < COLF; ++cf)
        woff[cf] = (size_t)(wbase + cf * 16 + m) * KP;

#pragma unroll 2
    for (int ks = 0; ks < 10; ++ks) {
        short8 a[RF];
#pragma unroll
        for (int rf = 0; rf < RF; ++rf) {
            int r = rf * 16 + m;
            int ch = ks * 4 + q;
            a[rf] = *(const short8*)&As[(size_t)(r * CH + (ch ^ (r & 7))) * 8];
        }
        int kb = ks * 32 + q * 8;
#pragma unroll
        for (int cf = 0; cf < COLF; ++cf) {
            short8 bh = *(const short8*)(Whi + woff[cf] + kb);
#pragma unroll
            for (int rf = 0; rf < RF; ++rf) {
                acc[rf][cf] = __builtin_amdgcn_mfma_f32_16x16x32_bf16(a[rf], bh, acc[rf][cf], 0, 0, 0);
            }
        }
    }

    __syncthreads();   // done reading As; reuse it as the write-back tile

    // ---- epilogue: D lane map col=lane&15, row=(lane>>4)*4+reg ----
    if constexpr (COLF == 5) {
        float sv[RF][4];
#pragma unroll
        for (int rf = 0; rf < RF; ++rf)
#pragma unroll
            for (int i = 0; i < 4; ++i) {
                int row = row0 + rf * 16 + q * 4 + i;
                sv[rf][i] = (row < N) ? svec[row] : 0.f;
            }
        int part = blockIdx.x & (NPART - 1);
#pragma unroll
        for (int cf = 0; cf < COLF; ++cf) {
            int col = wbase + cf * 16 + m;
            bool cok = col < EMB;
            float bia = cok ? bias[col] : 0.f;
            float lsum = 0.f, lsq = 0.f;
#pragma unroll
            for (int rf = 0; rf < RF; ++rf)
#pragma unroll
                for (int i = 0; i < 4; ++i) {
                    int r = rf * 16 + q * 4 + i;
                    int row = row0 + r;
                    float val = 0.f;
                    if (cok && row < N) {
                        val = acc[rf][cf][i] + bia + sv[rf][i];
                        lsum += val; lsq += val * val;
                    }
                    As[(size_t)r * WSTR + col] = f2bf(val);
                }
            lsum += __shfl_xor(lsum, 16); lsum += __shfl_xor(lsum, 32);
            lsq  += __shfl_xor(lsq, 16);  lsq  += __shfl_xor(lsq, 32);
            if (q == 0 && cok) {
                atomicAdd(&partsum[(size_t)part * KP + col], lsum);
                atomicAdd(&partsq[(size_t)part * KP + col], lsq);
            }
        }
    } else {
#pragma unroll
        for (int cf = 0; cf < COLF; ++cf) {
            int col = wbase + cf * 16 + m;
            float bia = bias[col];
#pragma unroll
            for (int rf = 0; rf < RF; ++rf)
#pragma unroll
                for (int i = 0; i < 4; ++i) {
                    int r = rf * 16 + q * 4 + i;
                    As[(size_t)r * WSTR + col] = f2bf(acc[rf][cf][i] + bia);
                }
        }
    }
    __syncthreads();

    // ---- contiguous write-back: BMT*WSTR bf16, full 16B chunks ----
    unsigned short* dst = OutB + (size_t)row0 * WSTR;
    for (int idx = tid; idx < BMT * WSTR / 8; idx += 256) {
        *(short8*)(dst + (size_t)idx * 8) = *(const short8*)&As[(size_t)idx * 8];
    }
}

// ---------------- BN reduce: one block per feature, wave shfl-reduce over partials ----
__global__ __launch_bounds__(64) void k_bnred(
    const float* __restrict__ partsum, const float* __restrict__ partsq,
    const float* __restrict__ gamma, const float* __restrict__ beta,
    float* __restrict__ scale, float* __restrict__ shift, int N) {
    int j = blockIdx.x;            // 0..KP-1
    int p = threadIdx.x;           // 0..63 = NPART
    if (j >= EMB) {
        if (p == 0) { scale[j] = 0.f; shift[j] = 0.f; }
        return;
    }
    float s = partsum[(size_t)p * KP + j];
    float sq = partsq[(size_t)p * KP + j];
#pragma unroll
    for (int off = 32; off > 0; off >>= 1) {
        s += __shfl_down(s, off);
        sq += __shfl_down(sq, off);
    }
    if (p == 0) {
        float invN = 1.0f / (float)N;
        float mean = s * invN;
        float var = sq * invN - mean * mean;
        float sc = gamma[j] * rsqrtf(var + BNEPS);
        scale[j] = sc;
        shift[j] = beta[j] - mean * sc;
    }
}

// ---------------- pooling over sorted batch (run-length compressed atomics) -------------
#define PROWS 128
__global__ __launch_bounds__(256) void k_pool(const unsigned short* __restrict__ H,
                                              const int* __restrict__ batch,
                                              float* __restrict__ gsums,
                                              float* __restrict__ counts, int N) {
    int j = threadIdx.x;
    int r0 = blockIdx.x * PROWS;
    int rend = min(r0 + PROWS, N);
    float run = 0.f;
    int runlen = 0;
    int curg = -1;
    for (int r = r0; r < rend; ++r) {
        int g = batch[r];
        if (g != curg) {
            if (curg >= 0) {
                atomicAdd(&gsums[(size_t)curg * FEAT + j], run);
                if (j == 0) atomicAdd(&counts[curg], (float)runlen);
            }
            curg = g; run = 0.f; runlen = 0;
        }
        run += bf2f(H[(size_t)r * FEAT + j]);
        ++runlen;
    }
    if (curg >= 0) {
        atomicAdd(&gsums[(size_t)curg * FEAT + j], run);
        if (j == 0) atomicAdd(&counts[curg], (float)runlen);
    }
}

// ---------------- pool-finalize + 2-layer MLP head, one block per graph ----------------
__global__ __launch_bounds__(128) void k_pred(
    const float* __restrict__ gsums, const float* __restrict__ counts,
    const float* __restrict__ w1, const float* __restrict__ b1,
    const float* __restrict__ w2, const float* __restrict__ b2,
    float* __restrict__ gout, float* __restrict__ pout) {
    __shared__ float gs[FEAT];
    __shared__ float h1[128];
    int g = blockIdx.x;
    float invc = 1.0f / fmaxf(counts[g], 1.0f);
    for (int k = threadIdx.x; k < FEAT; k += 128) {
        float val = gsums[(size_t)g * FEAT + k] * invc;
        gs[k] = val;
        gout[(size_t)g * FEAT + k] = val;
    }
    __syncthreads();
    int j = threadIdx.x;
    float acc = b1[j];
    for (int k = 0; k < FEAT; ++k) acc = fmaf(gs[k], w1[(size_t)k * 128 + j], acc);
    h1[j] = fmaxf(acc, 0.f);
    __syncthreads();
    if (j < 2) {
        float acc2 = b2[j];
        for (int k = 0; k < 128; ++k) acc2 = fmaf(h1[k], w2[k * 2 + j], acc2);
        pout[(size_t)g * 2 + j] = acc2;
    }
}

extern "C" void kernel_launch(void* const* d_in, const int* in_sizes, int n_in,
                              void* d_out, int out_size, void* d_ws, size_t ws_size,
                              hipStream_t stream) {
    const int* x      = (const int*)d_in[0];
    const int* ei     = (const int*)d_in[1];
    const int* ea     = (const int*)d_in[2];
    const int* batch  = (const int*)d_in[3];
    const float* xemb1 = (const float*)d_in[4];
    const float* xemb2 = (const float*)d_in[5];
    const float* convw = (const float*)d_in[6];
    const float* convb = (const float*)d_in[7];
    const float* eemb1 = (const float*)d_in[8];
    const float* eemb2 = (const float*)d_in[9];
    const float* gamma = (const float*)d_in[10];
    const float* beta  = (const float*)d_in[11];
    const float* featw = (const float*)d_in[12];
    const float* featb = (const float*)d_in[13];
    const float* pw1   = (const float*)d_in[14];
    const float* pb1   = (const float*)d_in[15];
    const float* pw2   = (const float*)d_in[16];
    const float* pb2   = (const float*)d_in[17];

    int N = in_sizes[0] / 2;
    int E = in_sizes[1] / 2;
    int nrb = (N + 127) / 128;            // both GEMMs use BMT=128
    size_t Npad = (size_t)nrb * 128;

    char* p = (char*)d_ws;
    auto alloc = [&](size_t bytes) { char* r = p; p += (bytes + 255) & ~255ull; return r; };
    // H0 (layer-0 input) and Hf (feature output) have disjoint live ranges -> share 64MB.
    unsigned short* H0Hf = (unsigned short*)alloc(Npad * KP * 2);    // 64 MB shared
    unsigned short* Abf  = (unsigned short*)alloc(Npad * KP * 2);    // 64 MB
    unsigned short* OutB = (unsigned short*)alloc(Npad * KP * 2);    // 64 MB
    float* partsum = (float*)alloc((size_t)NLAYER * NPART * KP * 4);
    float* partsq  = (float*)alloc((size_t)NLAYER * NPART * KP * 4);
    char*  zero1_end = p;                                            // partsum..partsq contiguous
    float* sAll    = (float*)alloc((size_t)NLAYER * N * 4);          // fully overwritten by k_sexp
    float* scaleA  = (float*)alloc((size_t)NLAYER * KP * 4);
    float* shiftA  = (float*)alloc((size_t)NLAYER * KP * 4);
    unsigned short* Whi = (unsigned short*)alloc((size_t)1856 * KP * 2);
    int*   deg    = (int*)alloc((size_t)N * 4);                      // written by k_sexp
    int*   rowptr = (int*)alloc((size_t)(N + 1) * 4);
    int*   cursor = (int*)alloc((size_t)N * 4);
    int*   hist   = (int*)alloc((size_t)N * 12 * 4);
    char*  zero2_end = p;                                            // cursor..hist contiguous
    int*   esrc   = (int*)alloc((size_t)E * 4);
    float* gsums  = (float*)alloc((size_t)NGRAPH * FEAT * 4);
    float* counts = (float*)alloc(NGRAPH * 4);
    char*  zero3_end = p;                                            // gsums..counts contiguous
    int nb = (N + SCAN_B - 1) / SCAN_B;
    int*   bsum   = (int*)alloc((size_t)nb * 4);

    hipMemsetAsync(partsum, 0, (size_t)(zero1_end - (char*)partsum), stream);
    hipMemsetAsync(cursor, 0, (size_t)(zero2_end - (char*)cursor), stream);  // cursor+hist
    hipMemsetAsync(gsums, 0, (size_t)(zero3_end - (char*)gsums), stream);
    // DMA staging reads Abf tail rows unguarded -> keep them zero (aggV only writes rows <N)
    if (Npad > (size_t)N)
        hipMemsetAsync(Abf + (size_t)N * KP, 0, (Npad - (size_t)N) * KP * 2, stream);

    int tpb = 256;
    k_prepW<<<(1856 * KP + 255) / 256, 256, 0, stream>>>(convw, featw, Whi);
    k_hist<<<(E + 255) / 256, 256, 0, stream>>>(ei, ea, hist, E);
    k_sexp<<<(N + 255) / 256, 256, 0, stream>>>(hist, eemb1, eemb2, sAll, deg, N);
    k_scanA<<<nb, SCAN_B, 0, stream>>>(deg, bsum, N);
    k_scanB<<<1, 64, 0, stream>>>(bsum, nb, rowptr, N);
    k_scanC<<<nb, SCAN_B, 0, stream>>>(deg, bsum, rowptr, N);
    k_scatter<<<(E + tpb - 1) / tpb, tpb, 0, stream>>>(ei, rowptr, cursor, esrc, E);
    k_h0<<<(N * 160 + 255) / 256, 256, 0, stream>>>(x, xemb1, xemb2, H0Hf, N);

    int gagg = (N * CHW + 255) / 256;
    k_aggV<false><<<gagg, 256, 0, stream>>>(H0Hf, rowptr, esrc, nullptr, nullptr, Abf, N);

    for (int l = 0; l < NLAYER; ++l) {
        k_mm<5, 128, false><<<nrb, 256, 0, stream>>>(
            Abf, nullptr, nullptr,
            Whi + (size_t)l * KP * KP,
            convb + (size_t)l * EMB, sAll + (size_t)l * N,
            OutB,
            partsum + (size_t)l * NPART * KP, partsq + (size_t)l * NPART * KP, N);
        k_bnred<<<KP, 64, 0, stream>>>(
            partsum + (size_t)l * NPART * KP, partsq + (size_t)l * NPART * KP,
            gamma + (size_t)l * EMB, beta + (size_t)l * EMB,
            scaleA + (size_t)l * KP, shiftA + (size_t)l * KP, N);
        if (l < NLAYER - 1)
            k_aggV<true><<<gagg, 256, 0, stream>>>(OutB, rowptr, esrc,
                                                   scaleA + (size_t)l * KP, shiftA + (size_t)l * KP,
                                                   Abf, N);
    }

    k_mm<4, 128, true><<<nrb, 256, 0, stream>>>(
        OutB, scaleA + (size_t)4 * KP, shiftA + (size_t)4 * KP,
        Whi + (size_t)1600 * KP,
        featb, nullptr,
        H0Hf, nullptr, nullptr, N);

    float* gout = (float*)d_out;
    float* pout = gout + (size_t)NGRAPH * FEAT;
    k_pool<<<(N + PROWS - 1) / PROWS, 256, 0, stream>>>(H0Hf, batch, gsums, counts, N);
    k_pred<<<NGRAPH, 128, 0, stream>>>(gsums, counts, pw1, pb1, pw2, pb2, gout, pout);
}